// Round 2
// baseline (251.293 us; speedup 1.0000x reference)
//
#include <hip/hip_runtime.h>
#include <hip/hip_bf16.h>

// Problem: B=8, S=1024, EMBED=1024, DK=DV=512, M=64.
// Identity: landmark selection is a segment permutation P of k, so
// kernel_1 = K3 P^T, pinv(kernel_2) = P pinv(K3), and
// out = K3 K3+ K3 v = K3 v == softmax(q k^T) v  (standard attention).
#define SS   1024
#define DKK  512

typedef __hip_bfloat16 bf16;
typedef __attribute__((ext_vector_type(8))) short s16x8;   // 8 x bf16 (4 VGPRs)
typedef __attribute__((ext_vector_type(4))) float f32x4;

// ---- ws layout (byte offsets), total 76 MiB + flag ----
// staged bf16 inputs: X(z) 16 MiB each at 0/16/32 MiB; W(z) 1 MiB at 48+z MiB;
// b(z) 4 KiB slots at 51 MiB; flag at 51 MiB+16K; q 52 MiB; k 60 MiB;
// vT 68 MiB; logits 16 MiB at offset 0 (reuses staged Xq AFTER proj is done).
#define WS_X(z)  ((size_t)(z) << 24)
#define WS_W(z)  ((48ull << 20) + ((size_t)(z) << 20))
#define WS_B(z)  ((51ull << 20) + (size_t)(z) * 4096)
#define WS_FLAG  ((51ull << 20) + 16384)
#define WS_Q     (52ull << 20)
#define WS_K     (60ull << 20)
#define WS_VT    (68ull << 20)
#define WS_LG    (0ull)

__device__ __forceinline__ void async_ld16(const void* g, void* s) {
  __builtin_amdgcn_global_load_lds(
      (const __attribute__((address_space(1))) void*)g,
      (__attribute__((address_space(3))) void*)s, 16, 0, 0);
}

__device__ __forceinline__ unsigned short f2bfu(float f) {
  return __builtin_bit_cast(unsigned short, __float2bfloat16(f));
}
__device__ __forceinline__ float bfu2f(unsigned short u) {
  unsigned int i = ((unsigned int)u) << 16;
  return __builtin_bit_cast(float, i);
}

// Dtype probe: low 16 bits of each uint32. bf16-pair data -> low half is a
// bf16 (exp in [96,159] for ~all normal(0,1) samples). f32 data -> low half
// is uniform mantissa bits (~25% land in that range). flag: 1=bf16, 0=f32.
__global__ void detect_kernel(const unsigned int* __restrict__ w,
                              int* __restrict__ flag) {
  __shared__ int cnt;
  if (threadIdx.x == 0) cnt = 0;
  __syncthreads();
  int local = 0;
  for (int i = threadIdx.x; i < 4096; i += 256) {
    unsigned int e = (w[i] >> 7) & 0xffu;
    local += (e >= 96u && e <= 159u) ? 1 : 0;
  }
  atomicAdd(&cnt, local);
  __syncthreads();
  if (threadIdx.x == 0) *flag = (cnt > 2458) ? 1 : 0;   // 60% threshold
}

// Stage one tensor to bf16 (copy if already bf16, round if f32). n % 8 == 0.
__global__ __launch_bounds__(256)
void convert_kernel(const void* __restrict__ src, bf16* __restrict__ dst,
                    int n, const int* __restrict__ flag) {
  const int i = (blockIdx.x * 256 + threadIdx.x) * 8;
  if (i >= n) return;
  unsigned short* d = (unsigned short*)dst + i;
  if (*flag) {
    const ushort4* s = (const ushort4*)((const unsigned short*)src + i);
    ushort4 a = s[0], b = s[1];
    ((ushort4*)d)[0] = a; ((ushort4*)d)[1] = b;
  } else {
    const float4* s = (const float4*)((const float*)src + i);
    float4 a = s[0], b = s[1];
    ushort4 o0, o1;
    o0.x = f2bfu(a.x); o0.y = f2bfu(a.y); o0.z = f2bfu(a.z); o0.w = f2bfu(a.w);
    o1.x = f2bfu(b.x); o1.y = f2bfu(b.y); o1.z = f2bfu(b.z); o1.w = f2bfu(b.w);
    ((ushort4*)d)[0] = o0; ((ushort4*)d)[1] = o1;
  }
}

// C[128x128] += A[128xK] * B[128xK]^T (both K-contiguous). 4 waves (2x2),
// each owns 64x64 as 4x4 MFMA 16x16x32 accs. LDS via global_load_lds w=16,
// 16B k-chunks XOR-swizzled by row&7 to kill the 128B-row-stride conflict.
template<int K, int LDA, int LDB>
__device__ __forceinline__ void gemm_core(const bf16* __restrict__ A,
                                          const bf16* __restrict__ Bw,
                                          int bm, int bn,
                                          short* As, short* Bs,
                                          f32x4 acc[4][4])
{
  const int tid  = threadIdx.x;
  const int lane = tid & 63;
  const int wave = tid >> 6;
  const int l8   = lane >> 3;                 // row within 8-row group
  const int kch  = ((lane & 7) ^ l8) * 8;     // swizzled k-chunk (elements)
  const bf16* ag = A  + (size_t)(bm * 128 + wave * 32 + l8) * LDA + kch;
  const bf16* bg = Bw + (size_t)(bn * 128 + wave * 32 + l8) * LDB + kch;
  short* AsW = As + wave * 32 * 64;
  short* BsW = Bs + wave * 32 * 64;
  const int waveM = wave >> 1, waveN = wave & 1;
  const int l16  = lane & 15;
  const int quad = lane >> 4;
  const int xr   = l16 & 7;

  #pragma unroll
  for (int mi = 0; mi < 4; ++mi)
    #pragma unroll
    for (int ni = 0; ni < 4; ++ni)
      #pragma unroll
      for (int r = 0; r < 4; ++r) acc[mi][ni][r] = 0.0f;

  for (int kt = 0; kt < K / 64; ++kt) {
    #pragma unroll
    for (int j = 0; j < 4; ++j) async_ld16(ag + (size_t)j * 8 * LDA, AsW + j * 8 * 64);
    #pragma unroll
    for (int j = 0; j < 4; ++j) async_ld16(bg + (size_t)j * 8 * LDB, BsW + j * 8 * 64);
    ag += 64; bg += 64;
    __syncthreads();          // compiler drains vmcnt before s_barrier
    #pragma unroll
    for (int ks = 0; ks < 2; ++ks) {
      s16x8 af[4], bfv[4];
      #pragma unroll
      for (int mi = 0; mi < 4; ++mi) {
        const int row  = waveM * 64 + mi * 16 + l16;
        const int slot = (ks * 4 + quad) ^ xr;
        af[mi] = *(const s16x8*)&As[row * 64 + slot * 8];
      }
      #pragma unroll
      for (int ni = 0; ni < 4; ++ni) {
        const int row  = waveN * 64 + ni * 16 + l16;
        const int slot = (ks * 4 + quad) ^ xr;
        bfv[ni] = *(const s16x8*)&Bs[row * 64 + slot * 8];
      }
      #pragma unroll
      for (int mi = 0; mi < 4; ++mi)
        #pragma unroll
        for (int ni = 0; ni < 4; ++ni)
          acc[mi][ni] = __builtin_amdgcn_mfma_f32_16x16x32_bf16(
              af[mi], bfv[ni], acc[mi][ni], 0, 0, 0);
    }
    __syncthreads();
  }
}

// z=0: q = (Xq Wq^T + bq) * 512^-0.5 ; z=1: k = Xk Wk^T + bk ;
// z=2: vT[b][d][s] = (Xv Wv^T + bv)^T  (so PV is also a BT-GEMM)
__global__ __launch_bounds__(256, 2)
void proj_kernel(const bf16* __restrict__ X0, const bf16* __restrict__ W0,
                 const bf16* __restrict__ b0,
                 bf16* __restrict__ qo, bf16* __restrict__ ko,
                 bf16* __restrict__ vT, float qscale)
{
  __shared__ __align__(16) short As[128 * 64];
  __shared__ __align__(16) short Bs[128 * 64];
  const int z = blockIdx.z;
  const bf16* A    = X0 + (size_t)z * 8388608;
  const bf16* Bw   = W0 + (size_t)z * 524288;
  const bf16* bias = b0 + (size_t)z * 2048;
  f32x4 acc[4][4];
  gemm_core<1024, 1024, 1024>(A, Bw, blockIdx.x, blockIdx.y, As, Bs, acc);

  const int lane = threadIdx.x & 63;
  const int wave = threadIdx.x >> 6;
  const int waveM = wave >> 1, waveN = wave & 1;
  const int l16 = lane & 15, quad = lane >> 4;
  const int row0 = blockIdx.x * 128 + waveM * 64;
  const int col0 = blockIdx.y * 128 + waveN * 64;
  const float sc = (z == 0) ? qscale : 1.0f;
  bf16* C = (z == 0) ? qo : ko;
  #pragma unroll
  for (int ni = 0; ni < 4; ++ni) {
    const int col = col0 + ni * 16 + l16;
    const float bb = (float)bias[col];
    #pragma unroll
    for (int mi = 0; mi < 4; ++mi)
      #pragma unroll
      for (int r = 0; r < 4; ++r) {
        const int row = row0 + mi * 16 + quad * 4 + r;
        const float v = acc[mi][ni][r] + bb;
        if (z == 2)
          vT[((size_t)(row >> 10) * DKK + col) * SS + (row & (SS - 1))] =
              __float2bfloat16(v);
        else
          C[(size_t)row * DKK + col] = __float2bfloat16(v * sc);
      }
  }
}

// logits[b][s][t] = q[b][s] . k[b][t]  (bf16; softmax'd in place later)
__global__ __launch_bounds__(256, 2)
void scores_kernel(const bf16* __restrict__ q, const bf16* __restrict__ k,
                   bf16* __restrict__ lgB)
{
  __shared__ __align__(16) short As[128 * 64];
  __shared__ __align__(16) short Bs[128 * 64];
  const int z = blockIdx.z;
  f32x4 acc[4][4];
  gemm_core<512, 512, 512>(q + (size_t)z * SS * DKK, k + (size_t)z * SS * DKK,
                           blockIdx.x, blockIdx.y, As, Bs, acc);

  const int lane = threadIdx.x & 63;
  const int wave = threadIdx.x >> 6;
  const int waveM = wave >> 1, waveN = wave & 1;
  const int l16 = lane & 15, quad = lane >> 4;
  const int row0 = blockIdx.x * 128 + waveM * 64;
  const int col0 = blockIdx.y * 128 + waveN * 64;
  bf16* C = lgB + (size_t)z * SS * SS;
  #pragma unroll
  for (int ni = 0; ni < 4; ++ni) {
    const int col = col0 + ni * 16 + l16;
    #pragma unroll
    for (int mi = 0; mi < 4; ++mi)
      #pragma unroll
      for (int r = 0; r < 4; ++r) {
        const int row = row0 + mi * 16 + quad * 4 + r;
        C[(size_t)row * SS + col] = __float2bfloat16(acc[mi][ni][r]);
      }
  }
}

// In-place row softmax; one wave per 1024-wide bf16 row.
__global__ __launch_bounds__(256)
void softmax_kernel(unsigned short* __restrict__ Pm)
{
  const int lane = threadIdx.x & 63;
  const int wv   = threadIdx.x >> 6;
  const size_t row = (size_t)blockIdx.x * 4 + wv;
  ushort4* ptr = (ushort4*)(Pm + row * SS);
  ushort4 u[4];
  float x[16];
  #pragma unroll
  for (int i = 0; i < 4; ++i) u[i] = ptr[lane + i * 64];
  #pragma unroll
  for (int i = 0; i < 4; ++i) {
    x[i * 4 + 0] = bfu2f(u[i].x); x[i * 4 + 1] = bfu2f(u[i].y);
    x[i * 4 + 2] = bfu2f(u[i].z); x[i * 4 + 3] = bfu2f(u[i].w);
  }
  float m = x[0];
  #pragma unroll
  for (int i = 1; i < 16; ++i) m = fmaxf(m, x[i]);
  #pragma unroll
  for (int off = 32; off > 0; off >>= 1) m = fmaxf(m, __shfl_xor(m, off));
  float s = 0.f;
  #pragma unroll
  for (int i = 0; i < 16; ++i) { x[i] = __expf(x[i] - m); s += x[i]; }
  #pragma unroll
  for (int off = 32; off > 0; off >>= 1) s += __shfl_xor(s, off);
  const float rs = 1.0f / s;
  #pragma unroll
  for (int i = 0; i < 4; ++i) {
    ushort4 o;
    o.x = f2bfu(x[i * 4 + 0] * rs); o.y = f2bfu(x[i * 4 + 1] * rs);
    o.z = f2bfu(x[i * 4 + 2] * rs); o.w = f2bfu(x[i * 4 + 3] * rs);
    ptr[lane + i * 64] = o;
  }
}

// out[b][s][d] = sum_t P[b][s][t] * vT[b][d][t]; store f32 or bf16 per flag.
__global__ __launch_bounds__(256, 2)
void pv_kernel(const bf16* __restrict__ P, const bf16* __restrict__ vT,
               void* __restrict__ out, const int* __restrict__ flag)
{
  __shared__ __align__(16) short As[128 * 64];
  __shared__ __align__(16) short Bs[128 * 64];
  const int z = blockIdx.z;
  f32x4 acc[4][4];
  gemm_core<1024, 1024, 1024>(P + (size_t)z * SS * SS, vT + (size_t)z * DKK * SS,
                              blockIdx.x, blockIdx.y, As, Bs, acc);

  const int lane = threadIdx.x & 63;
  const int wave = threadIdx.x >> 6;
  const int waveM = wave >> 1, waveN = wave & 1;
  const int l16 = lane & 15, quad = lane >> 4;
  const int row0 = blockIdx.x * 128 + waveM * 64;
  const int col0 = blockIdx.y * 128 + waveN * 64;
  const bool bf16out = (*flag != 0);
  const size_t base = (size_t)z * SS * DKK;
  #pragma unroll
  for (int ni = 0; ni < 4; ++ni) {
    const int col = col0 + ni * 16 + l16;
    #pragma unroll
    for (int mi = 0; mi < 4; ++mi)
      #pragma unroll
      for (int r = 0; r < 4; ++r) {
        const int row = row0 + mi * 16 + quad * 4 + r;
        const size_t idx = base + (size_t)row * DKK + col;
        const float v = acc[mi][ni][r];
        if (bf16out) ((bf16*)out)[idx] = __float2bfloat16(v);
        else         ((float*)out)[idx] = v;
      }
  }
}

extern "C" void kernel_launch(void* const* d_in, const int* in_sizes, int n_in,
                              void* d_out, int out_size, void* d_ws, size_t ws_size,
                              hipStream_t stream)
{
  char* ws = (char*)d_ws;
  bf16* X0  = (bf16*)(ws + WS_X(0));
  bf16* W0  = (bf16*)(ws + WS_W(0));
  bf16* b0  = (bf16*)(ws + WS_B(0));
  int*  flg = (int*)(ws + WS_FLAG);
  bf16* q   = (bf16*)(ws + WS_Q);
  bf16* kk  = (bf16*)(ws + WS_K);
  bf16* vT  = (bf16*)(ws + WS_VT);
  bf16* lgB = (bf16*)(ws + WS_LG);

  const float qscale = 0.044194173824159216f;  // 512^-0.5

  dim3 blk(256, 1, 1);
  hipLaunchKernelGGL(detect_kernel, dim3(1, 1, 1), blk, 0, stream,
                     (const unsigned int*)d_in[0], flg);

  // d_in order: qin,kin,vin,Wq,bq,Wk,bk,Wv,bv
  const int NX = 8388608, NW = 524288, NB = 512;
  hipLaunchKernelGGL(convert_kernel, dim3(NX / 2048), blk, 0, stream,
                     d_in[0], (bf16*)(ws + WS_X(0)), NX, flg);
  hipLaunchKernelGGL(convert_kernel, dim3(NX / 2048), blk, 0, stream,
                     d_in[1], (bf16*)(ws + WS_X(1)), NX, flg);
  hipLaunchKernelGGL(convert_kernel, dim3(NX / 2048), blk, 0, stream,
                     d_in[2], (bf16*)(ws + WS_X(2)), NX, flg);
  hipLaunchKernelGGL(convert_kernel, dim3(NW / 2048), blk, 0, stream,
                     d_in[3], (bf16*)(ws + WS_W(0)), NW, flg);
  hipLaunchKernelGGL(convert_kernel, dim3(NW / 2048), blk, 0, stream,
                     d_in[5], (bf16*)(ws + WS_W(1)), NW, flg);
  hipLaunchKernelGGL(convert_kernel, dim3(NW / 2048), blk, 0, stream,
                     d_in[7], (bf16*)(ws + WS_W(2)), NW, flg);
  hipLaunchKernelGGL(convert_kernel, dim3(1), blk, 0, stream,
                     d_in[4], (bf16*)(ws + WS_B(0)), NB, flg);
  hipLaunchKernelGGL(convert_kernel, dim3(1), blk, 0, stream,
                     d_in[6], (bf16*)(ws + WS_B(1)), NB, flg);
  hipLaunchKernelGGL(convert_kernel, dim3(1), blk, 0, stream,
                     d_in[8], (bf16*)(ws + WS_B(2)), NB, flg);

  hipLaunchKernelGGL(proj_kernel, dim3(64, 4, 3), blk, 0, stream,
                     X0, W0, b0, q, kk, vT, qscale);
  hipLaunchKernelGGL(scores_kernel, dim3(8, 8, 8), blk, 0, stream, q, kk, lgB);
  hipLaunchKernelGGL(softmax_kernel, dim3(2048, 1, 1), blk, 0, stream,
                     (unsigned short*)lgB);
  hipLaunchKernelGGL(pv_kernel, dim3(8, 4, 8), blk, 0, stream,
                     lgB, vT, d_out, flg);
}

// Round 3
// 222.131 us; speedup vs baseline: 1.1313x; 1.1313x over previous
//
#include <hip/hip_runtime.h>
#include <hip/hip_bf16.h>

// Problem: B=8, S=1024, EMBED=1024, DK=DV=512, M=64. Inputs/outputs f32.
// Identity: landmark selection is a segment permutation P of k, so
// kernel_1 = K3 P^T, pinv(kernel_2) = P pinv(K3), and
// out = K3 K3+ K3 v = K3 v == softmax(q k^T) v  (standard attention).
#define SS   1024
#define DKK  512

typedef __hip_bfloat16 bf16;
typedef __attribute__((ext_vector_type(8))) short s16x8;   // 8 x bf16 (4 VGPRs)
typedef __attribute__((ext_vector_type(4))) float f32x4;

// ---- ws layout (byte offsets), 76 MiB ----
// staged bf16: X(z) 16 MiB at 0/16/32 MiB; W(z) 1 MiB at 48+z MiB;
// q 52 MiB; k 60 MiB; vT 68 MiB; logits 16 MiB at 0 (X0 dead after proj).
#define WS_X(z)  ((size_t)(z) << 24)
#define WS_W(z)  ((48ull << 20) + ((size_t)(z) << 20))
#define WS_Q     (52ull << 20)
#define WS_K     (60ull << 20)
#define WS_VT    (68ull << 20)
#define WS_LG    (0ull)

__device__ __forceinline__ void async_ld16(const void* g, void* s) {
  __builtin_amdgcn_global_load_lds(
      (const __attribute__((address_space(1))) void*)g,
      (__attribute__((address_space(3))) void*)s, 16, 0, 0);
}

__device__ __forceinline__ unsigned short f2bfu(float f) {
  return __builtin_bit_cast(unsigned short, __float2bfloat16(f));
}
__device__ __forceinline__ float bfu2f(unsigned short u) {
  unsigned int i = ((unsigned int)u) << 16;
  return __builtin_bit_cast(float, i);
}

// One kernel converts all 3 X tensors (8M elems, 4096 blocks each) and all
// 3 W tensors (512K elems, 256 blocks each) f32 -> bf16 into ws.
__global__ __launch_bounds__(256)
void convert_all(const float* __restrict__ x0, const float* __restrict__ x1,
                 const float* __restrict__ x2, const float* __restrict__ w0,
                 const float* __restrict__ w1, const float* __restrict__ w2,
                 char* __restrict__ ws)
{
  const int bx = blockIdx.x;
  const float* src; unsigned short* dst; int local;
  if (bx < 12288) {
    const int z = bx >> 12; local = bx & 4095;
    src = (z == 0) ? x0 : (z == 1) ? x1 : x2;
    dst = (unsigned short*)(ws + WS_X(z));
  } else {
    const int t = bx - 12288; const int z = t >> 8; local = t & 255;
    src = (z == 0) ? w0 : (z == 1) ? w1 : w2;
    dst = (unsigned short*)(ws + WS_W(z));
  }
  const int i = local * 2048 + threadIdx.x * 8;
  const float4* s = (const float4*)(src + i);
  float4 a = s[0], b = s[1];
  ushort4 o0, o1;
  o0.x = f2bfu(a.x); o0.y = f2bfu(a.y); o0.z = f2bfu(a.z); o0.w = f2bfu(a.w);
  o1.x = f2bfu(b.x); o1.y = f2bfu(b.y); o1.z = f2bfu(b.z); o1.w = f2bfu(b.w);
  ((ushort4*)(dst + i))[0] = o0;
  ((ushort4*)(dst + i))[1] = o1;
}

// C[BM x 128] = A[BM x K] * B[128 x K]^T (both K-contiguous). 4 waves (2x2);
// each wave owns (BM/2) x 64 as acc[BM/32][4] MFMA 16x16x32 tiles.
// LDS via global_load_lds w=16; lane i of the wave lands at base + i*16, so
// LDS[row l8][slot c] holds global chunk (c ^ l8): readers use
// slot = chunk ^ (row & 7)  (row&7 == l16&7 for all fragment rows).
template<int BM, int K, int LDA, int LDB>
__device__ __forceinline__ void gemm_core(const bf16* __restrict__ A,
                                          const bf16* __restrict__ Bw,
                                          int bm, int bn,
                                          short* As, short* Bs, f32x4* acc)
{
  constexpr int MI = BM / 32;         // acc tiles in M per wave
  constexpr int AR = BM / 4;          // A rows staged per wave
  const int tid  = threadIdx.x;
  const int lane = tid & 63;
  const int wave = tid >> 6;
  const int l8   = lane >> 3;
  const int kch  = ((lane & 7) ^ l8) * 8;     // swizzled k-chunk (elements)
  const bf16* ag = A  + (size_t)(bm * BM + wave * AR + l8) * LDA + kch;
  const bf16* bg = Bw + (size_t)(bn * 128 + wave * 32 + l8) * LDB + kch;
  short* AsW = As + wave * AR * 64;
  short* BsW = Bs + wave * 32 * 64;
  const int waveM = wave >> 1, waveN = wave & 1;
  const int l16  = lane & 15;
  const int quad = lane >> 4;
  const int xr   = l16 & 7;

  #pragma unroll
  for (int t = 0; t < MI * 4; ++t)
    #pragma unroll
    for (int r = 0; r < 4; ++r) acc[t][r] = 0.0f;

  for (int kt = 0; kt < K / 64; ++kt) {
    #pragma unroll
    for (int j = 0; j < AR / 8; ++j) async_ld16(ag + (size_t)j * 8 * LDA, AsW + j * 8 * 64);
    #pragma unroll
    for (int j = 0; j < 4; ++j)      async_ld16(bg + (size_t)j * 8 * LDB, BsW + j * 8 * 64);
    ag += 64; bg += 64;
    __syncthreads();          // drains vmcnt before s_barrier
    #pragma unroll
    for (int ks = 0; ks < 2; ++ks) {
      s16x8 af[MI], bfv[4];
      #pragma unroll
      for (int mi = 0; mi < MI; ++mi) {
        const int row  = waveM * (BM / 2) + mi * 16 + l16;
        const int slot = (ks * 4 + quad) ^ xr;
        af[mi] = *(const s16x8*)&As[row * 64 + slot * 8];
      }
      #pragma unroll
      for (int ni = 0; ni < 4; ++ni) {
        const int row  = waveN * 64 + ni * 16 + l16;
        const int slot = (ks * 4 + quad) ^ xr;
        bfv[ni] = *(const s16x8*)&Bs[row * 64 + slot * 8];
      }
      #pragma unroll
      for (int mi = 0; mi < MI; ++mi)
        #pragma unroll
        for (int ni = 0; ni < 4; ++ni)
          acc[mi * 4 + ni] = __builtin_amdgcn_mfma_f32_16x16x32_bf16(
              af[mi], bfv[ni], acc[mi * 4 + ni], 0, 0, 0);
    }
    __syncthreads();
  }
}

// z=0: q = (Xq Wq^T + bq) * 512^-0.5 ; z=1: k = Xk Wk^T + bk ;
// z=2: vT[b][d][s] = (Xv Wv^T + bv)^T  (so PV is also a BT-GEMM)
__global__ __launch_bounds__(256, 2)
void proj_kernel(const bf16* __restrict__ X0, const bf16* __restrict__ W0,
                 const float* __restrict__ bq, const float* __restrict__ bk,
                 const float* __restrict__ bv,
                 bf16* __restrict__ qo, bf16* __restrict__ ko,
                 bf16* __restrict__ vT, float qscale)
{
  __shared__ __align__(16) short As[128 * 64];
  __shared__ __align__(16) short Bs[128 * 64];
  const int z = blockIdx.z;
  const bf16* A  = X0 + (size_t)z * 8388608;
  const bf16* Bw = W0 + ((size_t)z << 19);
  const float* bias = (z == 0) ? bq : (z == 1) ? bk : bv;
  f32x4 acc[16];
  gemm_core<128, 1024, 1024, 1024>(A, Bw, blockIdx.x, blockIdx.y, As, Bs, acc);

  const int lane = threadIdx.x & 63;
  const int wave = threadIdx.x >> 6;
  const int waveM = wave >> 1, waveN = wave & 1;
  const int l16 = lane & 15, quad = lane >> 4;
  const int row0 = blockIdx.x * 128 + waveM * 64;
  const int col0 = blockIdx.y * 128 + waveN * 64;
  const float sc = (z == 0) ? qscale : 1.0f;
  bf16* C = (z == 0) ? qo : ko;
  #pragma unroll
  for (int ni = 0; ni < 4; ++ni) {
    const int col = col0 + ni * 16 + l16;
    const float bb = bias[col];
    #pragma unroll
    for (int mi = 0; mi < 4; ++mi)
      #pragma unroll
      for (int r = 0; r < 4; ++r) {
        const int row = row0 + mi * 16 + quad * 4 + r;
        const float v = acc[mi * 4 + ni][r] + bb;
        if (z == 2)
          vT[((size_t)(row >> 10) * DKK + col) * SS + (row & (SS - 1))] =
              __float2bfloat16(v);
        else
          C[(size_t)row * DKK + col] = __float2bfloat16(v * sc);
      }
  }
}

// logits[b][s][t] = q[b][s].k[b][t]; BM=64 tiles -> 1024 blocks.
__global__ __launch_bounds__(256, 4)
void scores_kernel(const bf16* __restrict__ q, const bf16* __restrict__ k,
                   bf16* __restrict__ lgB)
{
  __shared__ __align__(16) short As[64 * 64];
  __shared__ __align__(16) short Bs[128 * 64];
  const int z = blockIdx.z;
  f32x4 acc[8];
  gemm_core<64, 512, 512, 512>(q + (size_t)z * SS * DKK, k + (size_t)z * SS * DKK,
                               blockIdx.x, blockIdx.y, As, Bs, acc);

  const int lane = threadIdx.x & 63;
  const int wave = threadIdx.x >> 6;
  const int waveM = wave >> 1, waveN = wave & 1;
  const int l16 = lane & 15, quad = lane >> 4;
  const int row0 = blockIdx.x * 64 + waveM * 32;
  const int col0 = blockIdx.y * 128 + waveN * 64;
  bf16* C = lgB + (size_t)z * SS * SS;
  #pragma unroll
  for (int ni = 0; ni < 4; ++ni) {
    const int col = col0 + ni * 16 + l16;
    #pragma unroll
    for (int mi = 0; mi < 2; ++mi)
      #pragma unroll
      for (int r = 0; r < 4; ++r) {
        const int row = row0 + mi * 16 + quad * 4 + r;
        C[(size_t)row * SS + col] = __float2bfloat16(acc[mi * 4 + ni][r]);
      }
  }
}

// In-place row softmax; one wave per 1024-wide bf16 row.
__global__ __launch_bounds__(256)
void softmax_kernel(unsigned short* __restrict__ Pm)
{
  const int lane = threadIdx.x & 63;
  const int wv   = threadIdx.x >> 6;
  const size_t row = (size_t)blockIdx.x * 4 + wv;
  ushort4* ptr = (ushort4*)(Pm + row * SS);
  ushort4 u[4];
  float x[16];
  #pragma unroll
  for (int i = 0; i < 4; ++i) u[i] = ptr[lane + i * 64];
  #pragma unroll
  for (int i = 0; i < 4; ++i) {
    x[i * 4 + 0] = bfu2f(u[i].x); x[i * 4 + 1] = bfu2f(u[i].y);
    x[i * 4 + 2] = bfu2f(u[i].z); x[i * 4 + 3] = bfu2f(u[i].w);
  }
  float m = x[0];
  #pragma unroll
  for (int i = 1; i < 16; ++i) m = fmaxf(m, x[i]);
  #pragma unroll
  for (int off = 32; off > 0; off >>= 1) m = fmaxf(m, __shfl_xor(m, off));
  float s = 0.f;
  #pragma unroll
  for (int i = 0; i < 16; ++i) { x[i] = __expf(x[i] - m); s += x[i]; }
  #pragma unroll
  for (int off = 32; off > 0; off >>= 1) s += __shfl_xor(s, off);
  const float rs = 1.0f / s;
  #pragma unroll
  for (int i = 0; i < 4; ++i) {
    ushort4 o;
    o.x = f2bfu(x[i * 4 + 0] * rs); o.y = f2bfu(x[i * 4 + 1] * rs);
    o.z = f2bfu(x[i * 4 + 2] * rs); o.w = f2bfu(x[i * 4 + 3] * rs);
    ptr[lane + i * 64] = o;
  }
}

// out[b][s][d] = sum_t P[b][s][t] * vT[b][d][t]; f32 out. BM=64 -> 512 blocks.
__global__ __launch_bounds__(256, 4)
void pv_kernel(const bf16* __restrict__ P, const bf16* __restrict__ vT,
               float* __restrict__ out)
{
  __shared__ __align__(16) short As[64 * 64];
  __shared__ __align__(16) short Bs[128 * 64];
  const int z = blockIdx.z;
  f32x4 acc[8];
  gemm_core<64, 1024, 1024, 1024>(P + (size_t)z * SS * SS, vT + (size_t)z * DKK * SS,
                                  blockIdx.x, blockIdx.y, As, Bs, acc);

  const int lane = threadIdx.x & 63;
  const int wave = threadIdx.x >> 6;
  const int waveM = wave >> 1, waveN = wave & 1;
  const int l16 = lane & 15, quad = lane >> 4;
  const int row0 = blockIdx.x * 64 + waveM * 32;
  const int col0 = blockIdx.y * 128 + waveN * 64;
  float* C = out + (size_t)z * SS * DKK;
  #pragma unroll
  for (int ni = 0; ni < 4; ++ni) {
    const int col = col0 + ni * 16 + l16;
    #pragma unroll
    for (int mi = 0; mi < 2; ++mi)
      #pragma unroll
      for (int r = 0; r < 4; ++r) {
        const int row = row0 + mi * 16 + quad * 4 + r;
        C[(size_t)row * DKK + col] = acc[mi * 4 + ni][r];
      }
  }
}

extern "C" void kernel_launch(void* const* d_in, const int* in_sizes, int n_in,
                              void* d_out, int out_size, void* d_ws, size_t ws_size,
                              hipStream_t stream)
{
  char* ws = (char*)d_ws;
  bf16* X0  = (bf16*)(ws + WS_X(0));
  bf16* W0  = (bf16*)(ws + WS_W(0));
  bf16* q   = (bf16*)(ws + WS_Q);
  bf16* kk  = (bf16*)(ws + WS_K);
  bf16* vT  = (bf16*)(ws + WS_VT);
  bf16* lgB = (bf16*)(ws + WS_LG);

  const float qscale = 0.044194173824159216f;  // 512^-0.5

  dim3 blk(256, 1, 1);
  // d_in order: qin,kin,vin,Wq,bq,Wk,bk,Wv,bv (all f32)
  hipLaunchKernelGGL(convert_all, dim3(13056), blk, 0, stream,
                     (const float*)d_in[0], (const float*)d_in[1],
                     (const float*)d_in[2], (const float*)d_in[3],
                     (const float*)d_in[5], (const float*)d_in[7], ws);
  hipLaunchKernelGGL(proj_kernel, dim3(64, 4, 3), blk, 0, stream,
                     X0, W0, (const float*)d_in[4], (const float*)d_in[6],
                     (const float*)d_in[8], q, kk, vT, qscale);
  hipLaunchKernelGGL(scores_kernel, dim3(16, 8, 8), blk, 0, stream, q, kk, lgB);
  hipLaunchKernelGGL(softmax_kernel, dim3(2048, 1, 1), blk, 0, stream,
                     (unsigned short*)lgB);
  hipLaunchKernelGGL(pv_kernel, dim3(16, 4, 8), blk, 0, stream,
                     lgB, vT, (float*)d_out);
}